// Round 9
// baseline (681.296 us; speedup 1.0000x reference)
//
#include <hip/hip_runtime.h>
#include <hip/hip_bf16.h>
#include <math.h>

#define D_MODEL 1024
#define D_STATE 16
#define D_INNER 2048
#define DT_RANK 64
#define BATCH   2
#define SEQLEN  2048
#define NPROJ   96   // DT_RANK + 2*D_STATE
#define NCHUNK  16
#define CHUNK   128  // SEQLEN / NCHUNK

typedef __attribute__((ext_vector_type(8))) __bf16 bf16x8;
typedef __attribute__((ext_vector_type(4))) float f32x4;

__device__ __forceinline__ float silu_f(float x) { return x / (1.f + __expf(-x)); }

__device__ __forceinline__ void gload_lds16(const void* g, void* l) {
    __builtin_amdgcn_global_load_lds((const __attribute__((address_space(1))) void*)g,
                                     (__attribute__((address_space(3))) void*)l, 16, 0, 0);
}

// ---------------- bf16 MFMA NT GEMM: C[m,n] = sum_k A[m,k]*B[n,k] -------------
template<int RELU, int OUT_BF16>
__global__ __launch_bounds__(256) void gemm_bf16_k(
    const __bf16* __restrict__ A, const __bf16* __restrict__ B, void* __restrict__ Cv,
    int K, int lda, int ldb, int ldc, long long sB, long long sC)
{
    __shared__ alignas(16) __bf16 As[128 * 32];
    __shared__ alignas(16) __bf16 Bs[128 * 32];
    const int bz = blockIdx.z;
    B += (long long)bz * sB;
    const int m0 = blockIdx.y * 128, n0 = blockIdx.x * 128;
    const int tid = threadIdx.x;
    const int lane = tid & 63;
    const int wv = tid >> 6;
    const int wr = wv >> 1, wc = wv & 1;

    f32x4 acc[4][4];
    #pragma unroll
    for (int i = 0; i < 4; ++i)
        #pragma unroll
        for (int j = 0; j < 4; ++j) acc[i][j] = (f32x4){0.f, 0.f, 0.f, 0.f};

    const int ko = (lane >> 4) * 8;
    const int fr = lane & 15;

    for (int k0 = 0; k0 < K; k0 += 32) {
        #pragma unroll
        for (int q = 0; q < 2; ++q) {
            int f = tid + q * 256;
            int row = f >> 2, c16 = f & 3;
            gload_lds16(A + (long long)(m0 + row) * lda + k0 + c16 * 8, As + f * 8);
            gload_lds16(B + (long long)(n0 + row) * ldb + k0 + c16 * 8, Bs + f * 8);
        }
        __syncthreads();
        bf16x8 a[4], b[4];
        #pragma unroll
        for (int i = 0; i < 4; ++i) {
            a[i] = *(const bf16x8*)(As + (wr * 64 + i * 16 + fr) * 32 + ko);
            b[i] = *(const bf16x8*)(Bs + (wc * 64 + i * 16 + fr) * 32 + ko);
        }
        #pragma unroll
        for (int i = 0; i < 4; ++i)
            #pragma unroll
            for (int j = 0; j < 4; ++j)
                acc[i][j] = __builtin_amdgcn_mfma_f32_16x16x32_bf16(a[i], b[j], acc[i][j], 0, 0, 0);
        __syncthreads();
    }

    #pragma unroll
    for (int i = 0; i < 4; ++i) {
        const int row = m0 + wr * 64 + i * 16 + (lane >> 4) * 4;
        #pragma unroll
        for (int j = 0; j < 4; ++j) {
            const int col = n0 + wc * 64 + j * 16 + fr;
            #pragma unroll
            for (int r = 0; r < 4; ++r) {
                float v = acc[i][j][r];
                if (RELU) v = fmaxf(v, 0.f);
                if (OUT_BF16)
                    ((__bf16*)Cv)[(long long)bz * sC + (long long)(row + r) * ldc + col] = (__bf16)v;
                else
                    ((float*)Cv)[(long long)bz * sC + (long long)(row + r) * ldc + col] = v;
            }
        }
    }
}

// ---------------- f32 -> bf16 pack (8 per thread) ----------------
__global__ void cvt_bf16_k(const float* __restrict__ in, __bf16* __restrict__ out, int n8) {
    int i = blockIdx.x * 256 + threadIdx.x;
    if (i >= n8) return;
    const f32x4* p = (const f32x4*)in + (long long)i * 2;
    f32x4 v0 = p[0], v1 = p[1];
    bf16x8 o;
    o[0] = (__bf16)v0[0]; o[1] = (__bf16)v0[1]; o[2] = (__bf16)v0[2]; o[3] = (__bf16)v0[3];
    o[4] = (__bf16)v1[0]; o[5] = (__bf16)v1[1]; o[6] = (__bf16)v1[2]; o[7] = (__bf16)v1[3];
    ((bf16x8*)out)[i] = o;
}

// ---------------- generic fp32 NT GEMM (kept for small dt GEMM) ----------------
template<int RELU>
__global__ __launch_bounds__(256) void gemm_nt_k(
    const float* __restrict__ A, const float* __restrict__ B, float* __restrict__ C,
    int M, int N, int K, int lda, int ldb, int ldc,
    long long sA, long long sB, long long sC)
{
    __shared__ float As[16][68];
    __shared__ float Bs[16][68];
    const int bz = blockIdx.z;
    A += (long long)bz * sA; B += (long long)bz * sB; C += (long long)bz * sC;
    const int m0 = blockIdx.y * 64, n0 = blockIdx.x * 64;
    const int tid = threadIdx.x;
    const int lk = tid & 15, lr = tid >> 4;
    const int tx = tid & 15, ty = tid >> 4;
    float acc[4][4] = {};
    for (int k0 = 0; k0 < K; k0 += 16) {
        #pragma unroll
        for (int q = 0; q < 4; ++q) {
            int i = lr + q * 16;
            As[lk][i] = A[(long long)(m0 + i) * lda + k0 + lk];
            Bs[lk][i] = B[(long long)(n0 + i) * ldb + k0 + lk];
        }
        __syncthreads();
        #pragma unroll
        for (int k = 0; k < 16; ++k) {
            float a[4], b[4];
            #pragma unroll
            for (int j = 0; j < 4; ++j) { a[j] = As[k][ty*4+j]; b[j] = Bs[k][tx*4+j]; }
            #pragma unroll
            for (int i = 0; i < 4; ++i)
                #pragma unroll
                for (int j = 0; j < 4; ++j) acc[i][j] += a[i] * b[j];
        }
        __syncthreads();
    }
    #pragma unroll
    for (int i = 0; i < 4; ++i)
        #pragma unroll
        for (int j = 0; j < 4; ++j) {
            float v = acc[i][j];
            if (RELU) v = fmaxf(v, 0.f);
            C[(long long)(m0 + ty*4 + i) * ldc + n0 + tx*4 + j] = v;
        }
}

// ---------------- Aneg = -exp(A_log) ----------------
__global__ void aneg_k(const float* __restrict__ A_log, float* __restrict__ Aneg) {
    int i = blockIdx.x * 256 + threadIdx.x;
    if (i < D_INNER * D_STATE) Aneg[i] = -expf(A_log[i]);
}

// ---------------- depthwise causal conv(4) + bias + SiLU ----------------
__global__ void conv_silu_k(const float* __restrict__ xz, const float* __restrict__ cw,
                            const float* __restrict__ cb, float* __restrict__ u)
{
    int idx = blockIdx.x * 256 + threadIdx.x;
    int l = idx & (SEQLEN - 1);
    int d = (idx >> 11) & (D_INNER - 1);
    int b = idx >> 22;
    const float* xi = xz + ((long long)b * 2 * D_INNER + d) * SEQLEN;
    float acc = cb[d];
    #pragma unroll
    for (int k = 0; k < 4; ++k) {
        int t = l + k - 3;
        if (t >= 0) acc += xi[t] * cw[d * 4 + k];
    }
    u[idx] = silu_f(acc);
}

// ---------------- x_dbl[b,l,e] = sum_d u[b,d,l] * W_x[e,d] ----------------
__global__ __launch_bounds__(256) void xdbl_k(const float* __restrict__ u,
    const float* __restrict__ Wx, float* __restrict__ xdbl)
{
    __shared__ float Us[32][65];
    __shared__ float Ws[32][96];
    const int b = blockIdx.z;
    const int l0 = blockIdx.x * 64;
    const int k0base = blockIdx.y * 512;
    const int tid = threadIdx.x;
    const int lx = tid & 63, eg = tid >> 6;
    float acc[24] = {};
    for (int kc = 0; kc < 16; ++kc) {
        int k0 = k0base + kc * 32;
        #pragma unroll
        for (int q = 0; q < 8; ++q) {
            int f = tid + q * 256;
            int kk = f >> 6, l = f & 63;
            Us[kk][l] = u[((long long)b * D_INNER + k0 + kk) * SEQLEN + l0 + l];
        }
        #pragma unroll
        for (int q = 0; q < 12; ++q) {
            int f = tid + q * 256;
            int kk = f & 31, e = f >> 5;
            Ws[kk][e] = Wx[(long long)e * D_INNER + k0 + kk];
        }
        __syncthreads();
        #pragma unroll
        for (int kk = 0; kk < 32; ++kk) {
            float a = Us[kk][lx];
            #pragma unroll
            for (int j = 0; j < 24; ++j) acc[j] += a * Ws[kk][eg * 24 + j];
        }
        __syncthreads();
    }
    #pragma unroll
    for (int j = 0; j < 24; ++j)
        atomicAdd(&xdbl[((long long)b * SEQLEN + l0 + lx) * NPROJ + eg * 24 + j], acc[j]);
}

// ---------------- delta = softplus(dt + b_dt) in place ----------------
__global__ void softplus_k(float* __restrict__ dtb, const float* __restrict__ b_dt) {
    int idx = blockIdx.x * 256 + threadIdx.x;
    int d = (idx >> 11) & (D_INNER - 1);
    float v = dtb[idx] + b_dt[d];
    dtb[idx] = fmaxf(v, 0.f) + log1pf(expf(-fabsf(v)));
}

// ======== chunked selective scan: time-parallel via associative combine =======
// group gg = chain g (b*D_INNER+d) x chunk c. 16 lanes per group, 4 groups/wave.
// Phase 1: per-chunk summary (A = prod dA, S = scan from 0).
__global__ __launch_bounds__(64, 1) void scan_p1_k(const float* __restrict__ delta,
    const float* __restrict__ u, const float* __restrict__ xdbl,
    const float* __restrict__ Aneg, float* __restrict__ chA, float* __restrict__ chS)
{
    const int q = threadIdx.x >> 4;
    const int n = threadIdx.x & 15;
    const int gg = blockIdx.x * 4 + q;
    const int g = gg >> 4, c = gg & (NCHUNK - 1);
    const int b = g >> 11, d = g & (D_INNER - 1);
    const float a = Aneg[d * D_STATE + n];
    const long long base = (long long)g * SEQLEN + c * CHUNK;
    const float4* dv = (const float4*)(delta + base);
    const float4* uv = (const float4*)(u + base);
    const float* xb = xdbl + ((long long)b * SEQLEN + c * CHUNK) * NPROJ + DT_RANK + n;

    float4 pd[4], pu[4];
    float pB[16];
    #pragma unroll
    for (int i = 0; i < 4; ++i) { pd[i] = dv[i]; pu[i] = uv[i]; }
    #pragma unroll
    for (int i = 0; i < 16; ++i) pB[i] = xb[i * NPROJ];

    float s = 0.f, ap = 1.f;
    for (int t0 = 0; t0 < CHUNK; t0 += 16) {
        float cd[16], cu[16], cB[16];
        #pragma unroll
        for (int i = 0; i < 4; ++i) {
            cd[4*i] = pd[i].x; cd[4*i+1] = pd[i].y; cd[4*i+2] = pd[i].z; cd[4*i+3] = pd[i].w;
            cu[4*i] = pu[i].x; cu[4*i+1] = pu[i].y; cu[4*i+2] = pu[i].z; cu[4*i+3] = pu[i].w;
        }
        #pragma unroll
        for (int i = 0; i < 16; ++i) cB[i] = pB[i];
        if (t0 + 16 < CHUNK) {
            const int nb = (t0 >> 2) + 4;
            #pragma unroll
            for (int i = 0; i < 4; ++i) { pd[i] = dv[nb + i]; pu[i] = uv[nb + i]; }
            const float* xn = xb + (t0 + 16) * NPROJ;
            #pragma unroll
            for (int i = 0; i < 16; ++i) pB[i] = xn[i * NPROJ];
        }
        float dA[16], wB[16];
        #pragma unroll
        for (int i = 0; i < 16; ++i) {
            dA[i] = __expf(cd[i] * a);
            wB[i] = cd[i] * cu[i] * cB[i];
        }
        #pragma unroll
        for (int i = 0; i < 16; ++i) {
            s = dA[i] * s + wB[i];
            ap *= dA[i];
        }
    }
    chA[(long long)gg * 16 + n] = ap;
    chS[(long long)gg * 16 + n] = s;
}

// Phase 2: serial combine of 16 chunk summaries per (chain, n) -> chunk entry states.
__global__ void scan_comb_k(const float* __restrict__ chA, const float* __restrict__ chS,
                            float* __restrict__ sinit)
{
    int idx = blockIdx.x * 256 + threadIdx.x;      // (g, n), 65536 total
    int g = idx >> 4, n = idx & 15;
    const float* A = chA + (long long)g * (NCHUNK * 16) + n;
    const float* S = chS + (long long)g * (NCHUNK * 16) + n;
    float av[NCHUNK], sv[NCHUNK];
    #pragma unroll
    for (int c = 0; c < NCHUNK; ++c) { av[c] = A[c * 16]; sv[c] = S[c * 16]; }
    float* si = sinit + (long long)g * (NCHUNK * 16) + n;
    float carry = 0.f;
    #pragma unroll
    for (int c = 0; c < NCHUNK; ++c) {
        si[c * 16] = carry;
        carry = sv[c] + av[c] * carry;
    }
}

// Phase 3: re-run recurrence per chunk from sinit, emit y via LDS transpose-reduce.
__global__ __launch_bounds__(64, 1) void scan_p3_k(const float* __restrict__ delta,
    const float* __restrict__ u, const float* __restrict__ xdbl,
    const float* __restrict__ Aneg, const float* __restrict__ sinit, float* __restrict__ y)
{
    __shared__ float lp[4][16][17];
    const int q = threadIdx.x >> 4;
    const int n = threadIdx.x & 15;
    const int gg = blockIdx.x * 4 + q;
    const int g = gg >> 4, c = gg & (NCHUNK - 1);
    const int b = g >> 11, d = g & (D_INNER - 1);
    const float a = Aneg[d * D_STATE + n];
    const long long base = (long long)g * SEQLEN + c * CHUNK;
    const float4* dv = (const float4*)(delta + base);
    const float4* uv = (const float4*)(u + base);
    const float* xb = xdbl + ((long long)b * SEQLEN + c * CHUNK) * NPROJ + DT_RANK + n;
    float* yl = y + base;

    float4 pd[4], pu[4];
    float pB[16], pC[16];
    #pragma unroll
    for (int i = 0; i < 4; ++i) { pd[i] = dv[i]; pu[i] = uv[i]; }
    #pragma unroll
    for (int i = 0; i < 16; ++i) { pB[i] = xb[i * NPROJ]; pC[i] = xb[i * NPROJ + D_STATE]; }

    float s = sinit[(long long)gg * 16 + n];
    for (int t0 = 0; t0 < CHUNK; t0 += 16) {
        float cd[16], cu[16], cB[16], cC[16];
        #pragma unroll
        for (int i = 0; i < 4; ++i) {
            cd[4*i] = pd[i].x; cd[4*i+1] = pd[i].y; cd[4*i+2] = pd[i].z; cd[4*i+3] = pd[i].w;
            cu[4*i] = pu[i].x; cu[4*i+1] = pu[i].y; cu[4*i+2] = pu[i].z; cu[4*i+3] = pu[i].w;
        }
        #pragma unroll
        for (int i = 0; i < 16; ++i) { cB[i] = pB[i]; cC[i] = pC[i]; }
        if (t0 + 16 < CHUNK) {
            const int nb = (t0 >> 2) + 4;
            #pragma unroll
            for (int i = 0; i < 4; ++i) { pd[i] = dv[nb + i]; pu[i] = uv[nb + i]; }
            const float* xn = xb + (t0 + 16) * NPROJ;
            #pragma unroll
            for (int i = 0; i < 16; ++i) { pB[i] = xn[i * NPROJ]; pC[i] = xn[i * NPROJ + D_STATE]; }
        }
        float dA[16], wB[16];
        #pragma unroll
        for (int i = 0; i < 16; ++i) {
            dA[i] = __expf(cd[i] * a);
            wB[i] = cd[i] * cu[i] * cB[i];
        }
        #pragma unroll
        for (int i = 0; i < 16; ++i) {
            s = dA[i] * s + wB[i];
            lp[q][n][i] = s * cC[i];
        }
        __syncthreads();
        float v[16];
        #pragma unroll
        for (int j = 0; j < 16; ++j) v[j] = lp[q][j][n];
        float acc = 0.f;
        #pragma unroll
        for (int j = 0; j < 16; ++j) acc += v[j];
        yl[t0 + n] = acc;
        __syncthreads();
    }
}

// ---------------- S[b,l] = sum_d Dp[d]*u[b,d,l] ----------------
__global__ void ssum_k(const float* __restrict__ u, const float* __restrict__ Dp,
                       float* __restrict__ S)
{
    int li = blockIdx.x * 256 + threadIdx.x;
    int c = blockIdx.y;
    int b = li >> 11, l = li & (SEQLEN - 1);
    const float* up = u + (long long)b * D_INNER * SEQLEN + l;
    float acc = 0.f;
    for (int d = c * 256; d < c * 256 + 256; ++d)
        acc += Dp[d] * up[(long long)d * SEQLEN];
    atomicAdd(&S[li], acc);
}

// ---------------- y=(y+Dp*u)*silu(z), transposed into ycat16[...,:2048] -------
__global__ __launch_bounds__(256) void ytrans_k(const float* __restrict__ ysc,
    const float* __restrict__ u, const float* __restrict__ xz,
    const float* __restrict__ Dp, __bf16* __restrict__ ycat)
{
    __shared__ float tile[32][33];
    const int b = blockIdx.z;
    const int d0 = blockIdx.y * 32, l0 = blockIdx.x * 32;
    const int lx = threadIdx.x, dy = threadIdx.y;
    #pragma unroll
    for (int j = 0; j < 4; ++j) {
        int d = d0 + dy + j * 8;
        long long i  = ((long long)b * D_INNER + d) * SEQLEN + l0 + lx;
        long long iz = ((long long)b * 2 * D_INNER + D_INNER + d) * SEQLEN + l0 + lx;
        tile[dy + j * 8][lx] = (ysc[i] + Dp[d] * u[i]) * silu_f(xz[iz]);
    }
    __syncthreads();
    #pragma unroll
    for (int j = 0; j < 4; ++j) {
        int l = l0 + dy + j * 8;
        ycat[((long long)b * SEQLEN + l) * (2 * D_INNER) + d0 + lx] = (__bf16)tile[lx][dy + j * 8];
    }
}

// ---------------- y_t -> ycat16[...,2048:] ----------------
__global__ __launch_bounds__(256) void yt_k(const float* __restrict__ xdbl,
    const float* __restrict__ Aneg, const float* __restrict__ S, __bf16* __restrict__ ycat)
{
    __shared__ float Cs[16][33];
    __shared__ float An[16][64];
    __shared__ float Sv[32];
    const int b = blockIdx.z;
    const int d0 = blockIdx.y * 64, l0 = blockIdx.x * 32;
    const int tid = threadIdx.x;
    for (int f = tid; f < 512; f += 256) {
        int n = f & 15, l = f >> 4;
        Cs[n][l] = xdbl[((long long)b * SEQLEN + l0 + l) * NPROJ + DT_RANK + D_STATE + n];
    }
    for (int f = tid; f < 1024; f += 256) {
        int n = f & 15, d = f >> 4;
        An[n][d] = Aneg[(d0 + d) * D_STATE + n];
    }
    if (tid < 32) Sv[tid] = S[b * SEQLEN + l0 + tid];
    __syncthreads();
    const int dx = tid & 63, lg = tid >> 6;
    #pragma unroll
    for (int j = 0; j < 8; ++j) {
        int l = lg * 8 + j;
        float acc = Sv[l];
        #pragma unroll
        for (int n = 0; n < 16; ++n) acc += Cs[n][l] * An[n][dx];
        ycat[((long long)b * SEQLEN + l0 + l) * (2 * D_INNER) + D_INNER + d0 + dx] = (__bf16)acc;
    }
}

extern "C" void kernel_launch(void* const* d_in, const int* in_sizes, int n_in,
                              void* d_out, int out_size, void* d_ws, size_t ws_size,
                              hipStream_t stream)
{
    const float* x      = (const float*)d_in[0];
    const float* W_in   = (const float*)d_in[1];
    const float* conv_w = (const float*)d_in[2];
    const float* conv_b = (const float*)d_in[3];
    const float* W_x    = (const float*)d_in[4];
    const float* W_dt   = (const float*)d_in[5];
    const float* b_dt   = (const float*)d_in[6];
    const float* A_log  = (const float*)d_in[7];
    const float* Dp     = (const float*)d_in[8];
    const float* W_out1 = (const float*)d_in[9];
    const float* W_out2 = (const float*)d_in[10];
    float* out = (float*)d_out;
    float* ws  = (float*)d_ws;

    // fp32 region (169.5 MB)
    float* xz   = ws;                    // 16777216
    float* u    = xz   + 16777216;       //  8388608
    float* xdbl = u    + 8388608;        //   393216
    float* dtb  = xdbl + 393216;         //  8388608 (delta)
    float* ysc  = dtb  + 8388608;        //  8388608
    float* Aneg = ysc  + 8388608;        //    32768
    float* S    = Aneg + 32768;          //     4096
    // bf16 tail (50.4 MB)
    __bf16* ycat16 = (__bf16*)(S + 4096);          // 16777216 el
    __bf16* h16    = ycat16 + 16777216;            //  8388608 el
    // overlays (regions dead at time of use)
    __bf16* W_in16  = (__bf16*)u;                  // before conv writes u
    __bf16* xb16    = W_in16 + 4194304;
    __bf16* Wout116 = (__bf16*)dtb;                // after scan reads dtb
    __bf16* Wout216 = Wout116 + 8388608;
    // scan summaries overlay ycat16's space (12 MB < 33.5 MB; ycat written later)
    float* chA    = (float*)ycat16;                // 4096*16*16 = 1048576
    float* chS    = chA + 1048576;                 // 1048576
    float* sinitb = chS + 1048576;                 // 1048576

    hipMemsetAsync(xdbl, 0, 393216 * sizeof(float), stream);
    hipMemsetAsync(S, 0, 4096 * sizeof(float), stream);
    aneg_k<<<128, 256, 0, stream>>>(A_log, Aneg);

    // bf16 conversions for input GEMM
    cvt_bf16_k<<<2048, 256, 0, stream>>>(W_in, W_in16, 524288);
    cvt_bf16_k<<<2048, 256, 0, stream>>>(x, xb16, 524288);

    // xz[b,e,l] = sum_d W_in[e,d] * x[b,l,d]   (M=4096, N=2048, K=1024)
    gemm_bf16_k<0, 0><<<dim3(16, 32, BATCH), 256, 0, stream>>>(
        W_in16, xb16, xz, D_MODEL, D_MODEL, D_MODEL, SEQLEN,
        (long long)SEQLEN * D_MODEL, (long long)4096 * SEQLEN);

    conv_silu_k<<<(BATCH * D_INNER * SEQLEN) / 256, 256, 0, stream>>>(xz, conv_w, conv_b, u);

    xdbl_k<<<dim3(SEQLEN / 64, 4, BATCH), 256, 0, stream>>>(u, W_x, xdbl);

    // dt[b,d,l] = sum_r W_dt[d,r] * x_dbl[b,l,r]   (small K=64, fp32)
    gemm_nt_k<0><<<dim3(SEQLEN / 64, D_INNER / 64, BATCH), 256, 0, stream>>>(
        W_dt, xdbl, dtb, D_INNER, SEQLEN, DT_RANK, DT_RANK, NPROJ, SEQLEN,
        0LL, (long long)SEQLEN * NPROJ, (long long)D_INNER * SEQLEN);

    softplus_k<<<(BATCH * D_INNER * SEQLEN) / 256, 256, 0, stream>>>(dtb, b_dt);

    // chunked scan: 16x time-parallel
    scan_p1_k<<<(BATCH * D_INNER * NCHUNK) / 4, 64, 0, stream>>>(dtb, u, xdbl, Aneg, chA, chS);
    scan_comb_k<<<256, 256, 0, stream>>>(chA, chS, sinitb);
    scan_p3_k<<<(BATCH * D_INNER * NCHUNK) / 4, 64, 0, stream>>>(dtb, u, xdbl, Aneg, sinitb, ysc);

    // weight conversions for output GEMMs (dtb region dead now)
    cvt_bf16_k<<<4096, 256, 0, stream>>>(W_out1, Wout116, 1048576);
    cvt_bf16_k<<<1024, 256, 0, stream>>>(W_out2, Wout216, 262144);

    ssum_k<<<dim3((BATCH * SEQLEN) / 256, 8), 256, 0, stream>>>(u, Dp, S);

    ytrans_k<<<dim3(SEQLEN / 32, D_INNER / 32, BATCH), dim3(32, 8), 0, stream>>>(ysc, u, xz, Dp, ycat16);

    yt_k<<<dim3(SEQLEN / 32, D_INNER / 64, BATCH), 256, 0, stream>>>(xdbl, Aneg, S, ycat16);

    // h = relu(ycat @ W_out1^T) -> bf16   (M=4096, N=2048, K=4096)
    gemm_bf16_k<1, 1><<<dim3(16, 32, 1), 256, 0, stream>>>(
        ycat16, Wout116, h16, 2 * D_INNER, 2 * D_INNER, 2 * D_INNER, D_INNER, 0LL, 0LL);

    // out = h @ W_out2^T   (M=4096, N=1024, K=2048)
    gemm_bf16_k<0, 0><<<dim3(8, 32, 1), 256, 0, stream>>>(
        h16, Wout216, out, D_INNER, D_INNER, D_INNER, D_MODEL, 0LL, 0LL);
}